// Round 8
// baseline (578.363 us; speedup 1.0000x reference)
//
#include <hip/hip_runtime.h>
#include <math.h>

#define BATCH 16
#define NS 2048
#define NT 96
#define DIM 32
#define ROWL 2144   // NS+NT
#define EPSV 1e-30f

// Feature-plane layouts (bf16 hi/lo planes, ushort bit patterns):
// spatial row (stride 224): [0:32)=s [32:64)=3*n1 [64:96)=-3*n2 [96:128)=n2
//                           [128:160)=n1 [160:192)=q_st [192:224)=k_ts
// temporal row (stride 96): [0:32)=t [32:64)=q_ts [64:96)=k_st
#define FS_STRIDE 224
#define FT_STRIDE 96

typedef __attribute__((ext_vector_type(8))) short bf16x8;
typedef __attribute__((ext_vector_type(4))) float f32x4;

__device__ __forceinline__ ushort f2bf_rn(float x){
  uint u = __float_as_uint(x);
  return (ushort)((u + 0x7FFFu + ((u >> 16) & 1u)) >> 16);
}
__device__ __forceinline__ float bf2f(ushort h){
  return __uint_as_float(((uint)h) << 16);
}

// ---------------------------------------------------------------------------
// Pass 0: per-row transforms -> bf16 hi/lo feature planes (hi = rn(x),
// lo = rn(x - hi)) for bf16x3 MFMA (fp32-equivalent; drops only lo*lo).
// ---------------------------------------------------------------------------
__global__ __launch_bounds__(256) void feat_kernel(
    const float* __restrict__ sp, const float* __restrict__ tp,
    const float* __restrict__ Wss1, const float* __restrict__ Wss2,
    const float* __restrict__ Wqst, const float* __restrict__ bqst,
    const float* __restrict__ Wkst, const float* __restrict__ bkst,
    const float* __restrict__ Wqts, const float* __restrict__ bqts,
    const float* __restrict__ Wkts, const float* __restrict__ bkts,
    ushort* __restrict__ FShi, ushort* __restrict__ FSlo,
    ushort* __restrict__ FThi, ushort* __restrict__ FTlo)
{
  __shared__ float Wl[6*1056];   // [32][33]-padded
  __shared__ float bl[128];
  __shared__ float xl[8][32];
  const int tid = threadIdx.x;
  {
    const float* Ws[6] = {Wss1, Wss2, Wqst, Wkst, Wqts, Wkts};
    #pragma unroll
    for (int m = 0; m < 6; m++){
      const float* W = Ws[m];
      #pragma unroll
      for (int c = 0; c < 4; c++){
        int idx = c*256 + tid;
        Wl[m*1056 + (idx>>5)*33 + (idx&31)] = W[idx];
      }
    }
    if (tid < 32)        bl[tid] = bqst[tid];
    else if (tid < 64)   bl[tid] = bkst[tid-32];
    else if (tid < 96)   bl[tid] = bqts[tid-64];
    else if (tid < 128)  bl[tid] = bkts[tid-96];
  }
  const int rs = tid >> 5;
  const int f  = tid & 31;
  const int row = blockIdx.x*8 + rs;
  const int NROWS = BATCH*NS;
  const int TOT   = NROWS + BATCH*NT;
  const bool valid = row < TOT;
  const bool isS   = row < NROWS;
  if (valid){
    const float* xp = isS ? (sp + (size_t)row*DIM) : (tp + (size_t)(row-NROWS)*DIM);
    xl[rs][f] = xp[f];
  }
  __syncthreads();
  if (!valid) return;

  if (isS){
    float a1=0.f, a2=0.f, aq=0.f, ak=0.f;
    #pragma unroll
    for (int d=0; d<32; d++){
      float xv = xl[rs][d];
      a1 = fmaf(xv, Wl[0*1056 + f*33 + d], a1);
      a2 = fmaf(xv, Wl[1*1056 + f*33 + d], a2);
      aq = fmaf(xv, Wl[2*1056 + f*33 + d], aq);
      ak = fmaf(xv, Wl[5*1056 + f*33 + d], ak);
    }
    float n1 = tanhf(3.0f*a1);
    float n2 = tanhf(3.0f*a2);
    float vals[7];
    vals[0] = xl[rs][f];        // s
    vals[1] = 3.0f*n1;          // 3*n1
    vals[2] = -3.0f*n2;         // -3*n2
    vals[3] = n2;
    vals[4] = n1;
    vals[5] = aq + bl[0  + f];  // q_st
    vals[6] = ak + bl[96 + f];  // k_ts
    ushort* oh = FShi + (size_t)row*FS_STRIDE + f;
    ushort* ol = FSlo + (size_t)row*FS_STRIDE + f;
    #pragma unroll
    for (int sgm = 0; sgm < 7; sgm++){
      float x = vals[sgm];
      ushort h = f2bf_rn(x);
      oh[sgm*32] = h;
      ol[sgm*32] = f2bf_rn(x - bf2f(h));
    }
  } else {
    const int rt = row - NROWS;
    float aq=0.f, ak=0.f;
    #pragma unroll
    for (int d=0; d<32; d++){
      float xv = xl[rs][d];
      aq = fmaf(xv, Wl[4*1056 + f*33 + d], aq);
      ak = fmaf(xv, Wl[3*1056 + f*33 + d], ak);
    }
    float vals[3];
    vals[0] = xl[rs][f];        // t
    vals[1] = aq + bl[64 + f];  // q_ts
    vals[2] = ak + bl[32 + f];  // k_st
    ushort* oh = FThi + (size_t)rt*FT_STRIDE + f;
    ushort* ol = FTlo + (size_t)rt*FT_STRIDE + f;
    #pragma unroll
    for (int sgm = 0; sgm < 3; sgm++){
      float x = vals[sgm];
      ushort h = f2bf_rn(x);
      oh[sgm*32] = h;
      ol[sgm*32] = f2bf_rn(x - bf2f(h));
    }
  }
}

// ---------------------------------------------------------------------------
// tanh on [0,1]: closed form with __expf, exact-range-safe (e^{2x} in [1,7.4])
// ---------------------------------------------------------------------------
__device__ __forceinline__ float tanh01(float x){
  float e = __expf(2.0f*x);
  return __fdividef(e - 1.0f, e + 1.0f);
}

// ---------------------------------------------------------------------------
// GEMM: 64(i) x 128(j) tile, bf16x3 MFMA, FRAGMENT-ORDER LDS (round-6 lesson:
// row-major LDS + b128 fragment reads = 8-way bank conflict; fragment-order
// makes the wave read base+lane*16B -- linear, conflict-free by construction).
// 4 waves as 2(row)x2(col); wave owns 32x64; per 32-k block 12 b128 reads ->
// 24 MFMAs. Whole K resident, single barrier; 72KB LDS @K=96 -> 2 blocks/CU.
//
// MODE 0 (max pass): NO stores -- only per-region relu-max via int-bits
//   atomicMax (relu>=0; 0xAA ws poison is a negative int so any update wins;
//   zero-padded OOB tiles give dot=0 which never raises a relu-max -> no
//   bounds checks at all).
// MODE 1 (norm pass): recompute the same products, read the region max, and
//   write tanh01(relu(v)/(max+eps)) directly to out (+ strict-lower-tri zero
//   when triu!=0). Raw adjacency never touches HBM: saves 2x294MB vs the
//   write-raw + read-modify-write scheme of rounds 3..6.
// ---------------------------------------------------------------------------
template<int NKB, int MODE>   // K = NKB*32
__global__ __launch_bounds__(256, 2) void adj_mfma(
    const ushort* __restrict__ Uhi, const ushort* __restrict__ Ulo, int ustride,
    int NI, int uo0, int uo1, int uo2,
    const ushort* __restrict__ Vhi, const ushort* __restrict__ Vlo, int vstride,
    int NJ, int vo0, int vo1, int vo2,
    float* __restrict__ out, int i0g, int j0g, float* __restrict__ maxslot,
    int triu)
{
  constexpr int ACELLS = 4*NKB*64;   // 4 rowgroups * NKB * 4q * 16r  (16B cells)
  constexpr int BCELLS = 8*NKB*64;   // 8 colgroups * NKB * 4q * 16r
  __shared__ __align__(16) ushort sAh[ACELLS*8];
  __shared__ __align__(16) ushort sAl[ACELLS*8];
  __shared__ __align__(16) ushort sBh[BCELLS*8];
  __shared__ __align__(16) ushort sBl[BCELLS*8];
  __shared__ float red[4];
  const int tid = threadIdx.x;
  const int b   = blockIdx.z;
  const int i0t = blockIdx.y*64;
  const int j0t = blockIdx.x*128;

  const ushort* Ubh = Uhi + (size_t)b*NI*ustride;
  const ushort* Ubl = Ulo + (size_t)b*NI*ustride;
  const ushort* Vbh = Vhi + (size_t)b*NJ*vstride;
  const ushort* Vbl = Vlo + (size_t)b*NJ*vstride;

  // ---- stage A (64 rows) ----
  for (int u = tid; u < ACELLS; u += 256){
    int q   = u & 3;
    int t   = u >> 2;
    int r15 = t & 15;
    int t2  = t >> 4;            // g*NKB + kb
    int kb  = t2 % NKB;
    int g   = t2 / NKB;
    int so  = (kb == 0) ? uo0 : ((kb == 1) ? uo1 : uo2);
    int gr  = i0t + g*16 + r15;
    uint4 vh = make_uint4(0u,0u,0u,0u), vl = vh;
    if (gr < NI){
      const size_t base = (size_t)gr*ustride + so + q*8;
      vh = *(const uint4*)(Ubh + base);
      vl = *(const uint4*)(Ubl + base);
    }
    int dcell = (t2*4 + q)*16 + r15;
    *(uint4*)&sAh[dcell*8] = vh;
    *(uint4*)&sAl[dcell*8] = vl;
  }
  // ---- stage B (128 cols) ----
  for (int u = tid; u < BCELLS; u += 256){
    int q   = u & 3;
    int t   = u >> 2;
    int r15 = t & 15;
    int t2  = t >> 4;            // g*NKB + kb
    int kb  = t2 % NKB;
    int g   = t2 / NKB;
    int so  = (kb == 0) ? vo0 : ((kb == 1) ? vo1 : vo2);
    int gr  = j0t + g*16 + r15;
    uint4 vh = make_uint4(0u,0u,0u,0u), vl = vh;
    if (gr < NJ){
      const size_t base = (size_t)gr*vstride + so + q*8;
      vh = *(const uint4*)(Vbh + base);
      vl = *(const uint4*)(Vbl + base);
    }
    int dcell = (t2*4 + q)*16 + r15;
    *(uint4*)&sBh[dcell*8] = vh;
    *(uint4*)&sBl[dcell*8] = vl;
  }
  __syncthreads();

  const int lane = tid & 63;
  const int w    = tid >> 6;
  const int wm   = w & 1;          // row half (32 rows)
  const int wn   = w >> 1;         // col half (64 cols)
  const int l15  = lane & 15;
  const int l4   = lane >> 4;

  f32x4 acc[2][4] = {};

  #pragma unroll
  for (int kb = 0; kb < NKB; ++kb){
    bf16x8 ah[2], al[2], bh[4], bl[4];
    #pragma unroll
    for (int m = 0; m < 2; m++){
      int off = ((2*wm + m)*NKB + kb)*512 + lane*8;
      ah[m] = *(const bf16x8*)&sAh[off];
      al[m] = *(const bf16x8*)&sAl[off];
    }
    #pragma unroll
    for (int n = 0; n < 4; n++){
      int off = ((4*wn + n)*NKB + kb)*512 + lane*8;
      bh[n] = *(const bf16x8*)&sBh[off];
      bl[n] = *(const bf16x8*)&sBl[off];
    }
    #pragma unroll
    for (int m = 0; m < 2; m++){
      #pragma unroll
      for (int n = 0; n < 4; n++){
        acc[m][n] = __builtin_amdgcn_mfma_f32_16x16x32_bf16(ah[m], bh[n], acc[m][n], 0,0,0);
        acc[m][n] = __builtin_amdgcn_mfma_f32_16x16x32_bf16(ah[m], bl[n], acc[m][n], 0,0,0);
        acc[m][n] = __builtin_amdgcn_mfma_f32_16x16x32_bf16(al[m], bh[n], acc[m][n], 0,0,0);
      }
    }
  }

  if (MODE == 0){
    // ---- max pass: relu-max only, no bounds checks (padded entries = 0) ----
    float lmax = 0.f;
    #pragma unroll
    for (int m = 0; m < 2; m++)
      #pragma unroll
      for (int n = 0; n < 4; n++)
        #pragma unroll
        for (int r = 0; r < 4; r++)
          lmax = fmaxf(lmax, acc[m][n][r]);
    #pragma unroll
    for (int off = 32; off > 0; off >>= 1)
      lmax = fmaxf(lmax, __shfl_xor(lmax, off));
    if ((tid & 63) == 0) red[tid >> 6] = lmax;
    __syncthreads();
    if (tid == 0){
      float m4 = fmaxf(fmaxf(red[0], red[1]), fmaxf(red[2], red[3]));
      atomicMax((int*)maxslot, __float_as_int(m4));
    }
  } else {
    // ---- norm pass: normalize + store (raw adj never hits HBM) ----
    const float rinv = 1.0f/(maxslot[0] + EPSV);
    const size_t obase = (size_t)b*ROWL*ROWL;
    #pragma unroll
    for (int m = 0; m < 2; m++){
      int gi_base = i0t + wm*32 + m*16 + l4*4;
      #pragma unroll
      for (int r = 0; r < 4; r++){
        int gi = gi_base + r;
        if (gi < NI){
          const size_t rowb = obase + (size_t)(i0g+gi)*ROWL + j0g;
          #pragma unroll
          for (int n = 0; n < 4; n++){
            int gj = j0t + wn*64 + n*16 + l15;
            if (gj < NJ){
              float v = tanh01(fmaxf(acc[m][n][r], 0.f)*rinv);
              if (triu && gj < gi) v = 0.f;
              out[rowb + gj] = v;
            }
          }
        }
      }
    }
  }
}

extern "C" void kernel_launch(void* const* d_in, const int* in_sizes, int n_in,
                              void* d_out, int out_size, void* d_ws, size_t ws_size,
                              hipStream_t stream)
{
  const float* sp   = (const float*)d_in[0];
  const float* tp   = (const float*)d_in[1];
  const float* Wss1 = (const float*)d_in[2];
  const float* Wss2 = (const float*)d_in[3];
  const float* Wqst = (const float*)d_in[4];
  const float* bqst = (const float*)d_in[5];
  const float* Wkst = (const float*)d_in[6];
  const float* bkst = (const float*)d_in[7];
  const float* Wqts = (const float*)d_in[8];
  const float* bqts = (const float*)d_in[9];
  const float* Wkts = (const float*)d_in[10];
  const float* bkts = (const float*)d_in[11];
  float* out  = (float*)d_out;
  float* wsf  = (float*)d_ws;
  float* maxs = wsf;                              // 4 relu-max slots

  const size_t SHROWS = (size_t)BATCH*NS;         // 32768
  const size_t STROWS = (size_t)BATCH*NT;         // 1536
  ushort* FShi = (ushort*)(wsf + 16);             // 64B-aligned
  ushort* FSlo = FShi + SHROWS*FS_STRIDE;
  ushort* FThi = FSlo + SHROWS*FS_STRIDE;
  ushort* FTlo = FThi + STROWS*FT_STRIDE;         // total ~30 MB

  feat_kernel<<<dim3((BATCH*(NS+NT))/8), 256, 0, stream>>>(
      sp,tp,Wss1,Wss2,Wqst,bqst,Wkst,bkst,Wqts,bqts,Wkts,bkts,
      FShi,FSlo,FThi,FTlo);

  // ---- phase 1: relu-max per region (no stores) ----
  adj_mfma<3,0><<<dim3(16,32,BATCH), 256, 0, stream>>>(   // ss K=96
      FShi,FSlo,FS_STRIDE,NS, 0,32,64,
      FShi,FSlo,FS_STRIDE,NS, 0,96,128,
      out, 0,0, maxs+0, 0);
  adj_mfma<2,0><<<dim3(1,32,BATCH), 256, 0, stream>>>(    // st K=64
      FShi,FSlo,FS_STRIDE,NS, 0,160,0,
      FThi,FTlo,FT_STRIDE,NT, 0,64,0,
      out, 0,NS, maxs+1, 0);
  adj_mfma<2,0><<<dim3(16,2,BATCH), 256, 0, stream>>>(    // ts K=64
      FThi,FTlo,FT_STRIDE,NT, 0,32,0,
      FShi,FSlo,FS_STRIDE,NS, 0,192,0,
      out, NS,0, maxs+2, 0);
  adj_mfma<1,0><<<dim3(1,2,BATCH), 256, 0, stream>>>(     // tt K=32
      FThi,FTlo,FT_STRIDE,NT, 0,0,0,
      FThi,FTlo,FT_STRIDE,NT, 0,0,0,
      out, NS,NS, maxs+3, 0);

  // ---- phase 2: recompute + normalize + store ----
  adj_mfma<3,1><<<dim3(16,32,BATCH), 256, 0, stream>>>(   // ss
      FShi,FSlo,FS_STRIDE,NS, 0,32,64,
      FShi,FSlo,FS_STRIDE,NS, 0,96,128,
      out, 0,0, maxs+0, 0);
  adj_mfma<2,1><<<dim3(1,32,BATCH), 256, 0, stream>>>(    // st
      FShi,FSlo,FS_STRIDE,NS, 0,160,0,
      FThi,FTlo,FT_STRIDE,NT, 0,64,0,
      out, 0,NS, maxs+1, 0);
  adj_mfma<2,1><<<dim3(16,2,BATCH), 256, 0, stream>>>(    // ts
      FThi,FTlo,FT_STRIDE,NT, 0,32,0,
      FShi,FSlo,FS_STRIDE,NS, 0,192,0,
      out, NS,0, maxs+2, 0);
  adj_mfma<1,1><<<dim3(1,2,BATCH), 256, 0, stream>>>(     // tt (+triu)
      FThi,FTlo,FT_STRIDE,NT, 0,0,0,
      FThi,FTlo,FT_STRIDE,NT, 0,0,0,
      out, NS,NS, maxs+3, 1);
}

// Round 9
// 573.706 us; speedup vs baseline: 1.0081x; 1.0081x over previous
//
#include <hip/hip_runtime.h>
#include <math.h>

#define BATCH 16
#define NS 2048
#define NT 96
#define DIM 32
#define ROWL 2144   // NS+NT
#define EPSV 1e-30f

// Feature-plane layouts (bf16 hi/lo planes, ushort bit patterns):
// spatial row (stride 224): [0:32)=s [32:64)=3*n1 [64:96)=-3*n2 [96:128)=n2
//                           [128:160)=n1 [160:192)=q_st [192:224)=k_ts
// temporal row (stride 96): [0:32)=t [32:64)=q_ts [64:96)=k_st
#define FS_STRIDE 224
#define FT_STRIDE 96

typedef __attribute__((ext_vector_type(8))) short bf16x8;
typedef __attribute__((ext_vector_type(4))) float f32x4;

__device__ __forceinline__ ushort f2bf_rn(float x){
  uint u = __float_as_uint(x);
  return (ushort)((u + 0x7FFFu + ((u >> 16) & 1u)) >> 16);
}
__device__ __forceinline__ float bf2f(ushort h){
  return __uint_as_float(((uint)h) << 16);
}

// ---------------------------------------------------------------------------
// Pass 0: per-row transforms -> bf16 hi/lo feature planes (hi = rn(x),
// lo = rn(x - hi)) for bf16x3 MFMA (fp32-equivalent; drops only lo*lo).
// ---------------------------------------------------------------------------
__global__ __launch_bounds__(256) void feat_kernel(
    const float* __restrict__ sp, const float* __restrict__ tp,
    const float* __restrict__ Wss1, const float* __restrict__ Wss2,
    const float* __restrict__ Wqst, const float* __restrict__ bqst,
    const float* __restrict__ Wkst, const float* __restrict__ bkst,
    const float* __restrict__ Wqts, const float* __restrict__ bqts,
    const float* __restrict__ Wkts, const float* __restrict__ bkts,
    ushort* __restrict__ FShi, ushort* __restrict__ FSlo,
    ushort* __restrict__ FThi, ushort* __restrict__ FTlo)
{
  __shared__ float Wl[6*1056];   // [32][33]-padded
  __shared__ float bl[128];
  __shared__ float xl[8][32];
  const int tid = threadIdx.x;
  {
    const float* Ws[6] = {Wss1, Wss2, Wqst, Wkst, Wqts, Wkts};
    #pragma unroll
    for (int m = 0; m < 6; m++){
      const float* W = Ws[m];
      #pragma unroll
      for (int c = 0; c < 4; c++){
        int idx = c*256 + tid;
        Wl[m*1056 + (idx>>5)*33 + (idx&31)] = W[idx];
      }
    }
    if (tid < 32)        bl[tid] = bqst[tid];
    else if (tid < 64)   bl[tid] = bkst[tid-32];
    else if (tid < 96)   bl[tid] = bqts[tid-64];
    else if (tid < 128)  bl[tid] = bkts[tid-96];
  }
  const int rs = tid >> 5;
  const int f  = tid & 31;
  const int row = blockIdx.x*8 + rs;
  const int NROWS = BATCH*NS;
  const int TOT   = NROWS + BATCH*NT;
  const bool valid = row < TOT;
  const bool isS   = row < NROWS;
  if (valid){
    const float* xp = isS ? (sp + (size_t)row*DIM) : (tp + (size_t)(row-NROWS)*DIM);
    xl[rs][f] = xp[f];
  }
  __syncthreads();
  if (!valid) return;

  if (isS){
    float a1=0.f, a2=0.f, aq=0.f, ak=0.f;
    #pragma unroll
    for (int d=0; d<32; d++){
      float xv = xl[rs][d];
      a1 = fmaf(xv, Wl[0*1056 + f*33 + d], a1);
      a2 = fmaf(xv, Wl[1*1056 + f*33 + d], a2);
      aq = fmaf(xv, Wl[2*1056 + f*33 + d], aq);
      ak = fmaf(xv, Wl[5*1056 + f*33 + d], ak);
    }
    float n1 = tanhf(3.0f*a1);
    float n2 = tanhf(3.0f*a2);
    float vals[7];
    vals[0] = xl[rs][f];        // s
    vals[1] = 3.0f*n1;          // 3*n1
    vals[2] = -3.0f*n2;         // -3*n2
    vals[3] = n2;
    vals[4] = n1;
    vals[5] = aq + bl[0  + f];  // q_st
    vals[6] = ak + bl[96 + f];  // k_ts
    ushort* oh = FShi + (size_t)row*FS_STRIDE + f;
    ushort* ol = FSlo + (size_t)row*FS_STRIDE + f;
    #pragma unroll
    for (int sgm = 0; sgm < 7; sgm++){
      float x = vals[sgm];
      ushort h = f2bf_rn(x);
      oh[sgm*32] = h;
      ol[sgm*32] = f2bf_rn(x - bf2f(h));
    }
  } else {
    const int rt = row - NROWS;
    float aq=0.f, ak=0.f;
    #pragma unroll
    for (int d=0; d<32; d++){
      float xv = xl[rs][d];
      aq = fmaf(xv, Wl[4*1056 + f*33 + d], aq);
      ak = fmaf(xv, Wl[3*1056 + f*33 + d], ak);
    }
    float vals[3];
    vals[0] = xl[rs][f];        // t
    vals[1] = aq + bl[64 + f];  // q_ts
    vals[2] = ak + bl[32 + f];  // k_st
    ushort* oh = FThi + (size_t)rt*FT_STRIDE + f;
    ushort* ol = FTlo + (size_t)rt*FT_STRIDE + f;
    #pragma unroll
    for (int sgm = 0; sgm < 3; sgm++){
      float x = vals[sgm];
      ushort h = f2bf_rn(x);
      oh[sgm*32] = h;
      ol[sgm*32] = f2bf_rn(x - bf2f(h));
    }
  }
}

// ---------------------------------------------------------------------------
// tanh on [0,1]: closed form with __expf, exact-range-safe (e^{2x} in [1,7.4])
// ---------------------------------------------------------------------------
__device__ __forceinline__ float tanh01(float x){
  float e = __expf(2.0f*x);
  return __fdividef(e - 1.0f, e + 1.0f);
}

// ---------------------------------------------------------------------------
// GEMM: 64(i) x 128(j) tile, bf16x3 MFMA, FRAGMENT-ORDER LDS (conflict-free
// b128 fragment reads: wave reads base+lane*16B, linear).
// MODE 0 (max pass): no stores; per-region relu-max via int-bits atomicMax.
// MODE 1 (norm pass): recompute, normalize, store.
//   Round-8 lesson: direct per-lane stores are 64B-fragmented (4 rows x 16
//   floats per instr) -> ~1/4 store efficiency; epilogue dominated the pass.
//   Fix: full tiles stage the 64x128 result in LDS (stride 132: writer lanes
//   4 rows apart get bank shifts {0,16} = free 2-way; float4-aligned), then
//   copy out with 32-lanes-per-row float4 stores = 512B-contiguous runs.
// ---------------------------------------------------------------------------
template<int NKB, int MODE>   // K = NKB*32
__global__ __launch_bounds__(256, 2) void adj_mfma(
    const ushort* __restrict__ Uhi, const ushort* __restrict__ Ulo, int ustride,
    int NI, int uo0, int uo1, int uo2,
    const ushort* __restrict__ Vhi, const ushort* __restrict__ Vlo, int vstride,
    int NJ, int vo0, int vo1, int vo2,
    float* __restrict__ out, int i0g, int j0g, float* __restrict__ maxslot,
    int triu)
{
  constexpr int ACELLS = 4*NKB*64;   // 4 rowgroups * NKB * 4q * 16r  (16B cells)
  constexpr int BCELLS = 8*NKB*64;   // 8 colgroups * NKB * 4q * 16r
  constexpr int STAGE_USH = (ACELLS + BCELLS)*2*8;  // hi+lo planes, ushorts
  constexpr int TILE_USH  = 64*132*2;               // 64x132 fp32 tile
  constexpr int SMEM_USH  = (STAGE_USH > TILE_USH) ? STAGE_USH : TILE_USH;
  __shared__ __align__(16) ushort smem[SMEM_USH];
  __shared__ float red[4];
  ushort* sAh = smem;
  ushort* sAl = smem + ACELLS*8;
  ushort* sBh = smem + 2*ACELLS*8;
  ushort* sBl = smem + 2*ACELLS*8 + BCELLS*8;

  const int tid = threadIdx.x;
  const int b   = blockIdx.z;
  const int i0t = blockIdx.y*64;
  const int j0t = blockIdx.x*128;

  const ushort* Ubh = Uhi + (size_t)b*NI*ustride;
  const ushort* Ubl = Ulo + (size_t)b*NI*ustride;
  const ushort* Vbh = Vhi + (size_t)b*NJ*vstride;
  const ushort* Vbl = Vlo + (size_t)b*NJ*vstride;

  // ---- stage A (64 rows) ----
  for (int u = tid; u < ACELLS; u += 256){
    int q   = u & 3;
    int t   = u >> 2;
    int r15 = t & 15;
    int t2  = t >> 4;            // g*NKB + kb
    int kb  = t2 % NKB;
    int g   = t2 / NKB;
    int so  = (kb == 0) ? uo0 : ((kb == 1) ? uo1 : uo2);
    int gr  = i0t + g*16 + r15;
    uint4 vh = make_uint4(0u,0u,0u,0u), vl = vh;
    if (gr < NI){
      const size_t base = (size_t)gr*ustride + so + q*8;
      vh = *(const uint4*)(Ubh + base);
      vl = *(const uint4*)(Ubl + base);
    }
    int dcell = (t2*4 + q)*16 + r15;
    *(uint4*)&sAh[dcell*8] = vh;
    *(uint4*)&sAl[dcell*8] = vl;
  }
  // ---- stage B (128 cols) ----
  for (int u = tid; u < BCELLS; u += 256){
    int q   = u & 3;
    int t   = u >> 2;
    int r15 = t & 15;
    int t2  = t >> 4;            // g*NKB + kb
    int kb  = t2 % NKB;
    int g   = t2 / NKB;
    int so  = (kb == 0) ? vo0 : ((kb == 1) ? vo1 : vo2);
    int gr  = j0t + g*16 + r15;
    uint4 vh = make_uint4(0u,0u,0u,0u), vl = vh;
    if (gr < NJ){
      const size_t base = (size_t)gr*vstride + so + q*8;
      vh = *(const uint4*)(Vbh + base);
      vl = *(const uint4*)(Vbl + base);
    }
    int dcell = (t2*4 + q)*16 + r15;
    *(uint4*)&sBh[dcell*8] = vh;
    *(uint4*)&sBl[dcell*8] = vl;
  }
  __syncthreads();

  const int lane = tid & 63;
  const int w    = tid >> 6;
  const int wm   = w & 1;          // row half (32 rows)
  const int wn   = w >> 1;         // col half (64 cols)
  const int l15  = lane & 15;
  const int l4   = lane >> 4;

  f32x4 acc[2][4] = {};

  #pragma unroll
  for (int kb = 0; kb < NKB; ++kb){
    bf16x8 ah[2], al[2], bh[4], bl[4];
    #pragma unroll
    for (int m = 0; m < 2; m++){
      int off = ((2*wm + m)*NKB + kb)*512 + lane*8;
      ah[m] = *(const bf16x8*)&sAh[off];
      al[m] = *(const bf16x8*)&sAl[off];
    }
    #pragma unroll
    for (int n = 0; n < 4; n++){
      int off = ((4*wn + n)*NKB + kb)*512 + lane*8;
      bh[n] = *(const bf16x8*)&sBh[off];
      bl[n] = *(const bf16x8*)&sBl[off];
    }
    #pragma unroll
    for (int m = 0; m < 2; m++){
      #pragma unroll
      for (int n = 0; n < 4; n++){
        acc[m][n] = __builtin_amdgcn_mfma_f32_16x16x32_bf16(ah[m], bh[n], acc[m][n], 0,0,0);
        acc[m][n] = __builtin_amdgcn_mfma_f32_16x16x32_bf16(ah[m], bl[n], acc[m][n], 0,0,0);
        acc[m][n] = __builtin_amdgcn_mfma_f32_16x16x32_bf16(al[m], bh[n], acc[m][n], 0,0,0);
      }
    }
  }

  if (MODE == 0){
    // ---- max pass: relu-max only, no bounds checks (padded entries = 0) ----
    float lmax = 0.f;
    #pragma unroll
    for (int m = 0; m < 2; m++)
      #pragma unroll
      for (int n = 0; n < 4; n++)
        #pragma unroll
        for (int r = 0; r < 4; r++)
          lmax = fmaxf(lmax, acc[m][n][r]);
    #pragma unroll
    for (int off = 32; off > 0; off >>= 1)
      lmax = fmaxf(lmax, __shfl_xor(lmax, off));
    if ((tid & 63) == 0) red[tid >> 6] = lmax;
    __syncthreads();
    if (tid == 0){
      float m4 = fmaxf(fmaxf(red[0], red[1]), fmaxf(red[2], red[3]));
      atomicMax((int*)maxslot, __float_as_int(m4));
    }
  } else {
    const float rinv = 1.0f/(maxslot[0] + EPSV);
    const size_t obase = (size_t)b*ROWL*ROWL;
    const bool full = (i0t + 64 <= NI) && (j0t + 128 <= NJ) && !triu;

    if (full){
      // ---- coalesced epilogue: stage tile in LDS, copy out as float4 ----
      __syncthreads();                       // staging LDS reuse is safe now
      float* tile = (float*)smem;            // [64][132]
      #pragma unroll
      for (int m = 0; m < 2; m++){
        int rbase = wm*32 + m*16 + l4*4;
        #pragma unroll
        for (int r = 0; r < 4; r++){
          int row = rbase + r;
          #pragma unroll
          for (int n = 0; n < 4; n++){
            int col = wn*64 + n*16 + l15;
            tile[row*132 + col] = tanh01(fmaxf(acc[m][n][r], 0.f)*rinv);
          }
        }
      }
      __syncthreads();
      const float* outrow0 = out + obase + (size_t)(i0g + i0t)*ROWL + (j0g + j0t);
      #pragma unroll
      for (int k = 0; k < 8; k++){
        int q    = k*256 + tid;              // 0..2047
        int row  = q >> 5;
        int col4 = q & 31;
        float4 v = *(const float4*)&tile[row*132 + col4*4];
        *(float4*)((float*)outrow0 + (size_t)row*ROWL + col4*4) = v;
      }
    } else {
      // ---- scalar fallback for edge tiles (+ tt triu) ----
      #pragma unroll
      for (int m = 0; m < 2; m++){
        int gi_base = i0t + wm*32 + m*16 + l4*4;
        #pragma unroll
        for (int r = 0; r < 4; r++){
          int gi = gi_base + r;
          if (gi < NI){
            const size_t rowb = obase + (size_t)(i0g+gi)*ROWL + j0g;
            #pragma unroll
            for (int n = 0; n < 4; n++){
              int gj = j0t + wn*64 + n*16 + l15;
              if (gj < NJ){
                float v = tanh01(fmaxf(acc[m][n][r], 0.f)*rinv);
                if (triu && gj < gi) v = 0.f;
                out[rowb + gj] = v;
              }
            }
          }
        }
      }
    }
  }
}

extern "C" void kernel_launch(void* const* d_in, const int* in_sizes, int n_in,
                              void* d_out, int out_size, void* d_ws, size_t ws_size,
                              hipStream_t stream)
{
  const float* sp   = (const float*)d_in[0];
  const float* tp   = (const float*)d_in[1];
  const float* Wss1 = (const float*)d_in[2];
  const float* Wss2 = (const float*)d_in[3];
  const float* Wqst = (const float*)d_in[4];
  const float* bqst = (const float*)d_in[5];
  const float* Wkst = (const float*)d_in[6];
  const float* bkst = (const float*)d_in[7];
  const float* Wqts = (const float*)d_in[8];
  const float* bqts = (const float*)d_in[9];
  const float* Wkts = (const float*)d_in[10];
  const float* bkts = (const float*)d_in[11];
  float* out  = (float*)d_out;
  float* wsf  = (float*)d_ws;
  float* maxs = wsf;                              // 4 relu-max slots

  const size_t SHROWS = (size_t)BATCH*NS;         // 32768
  const size_t STROWS = (size_t)BATCH*NT;         // 1536
  ushort* FShi = (ushort*)(wsf + 16);             // 64B-aligned
  ushort* FSlo = FShi + SHROWS*FS_STRIDE;
  ushort* FThi = FSlo + SHROWS*FS_STRIDE;
  ushort* FTlo = FThi + STROWS*FT_STRIDE;         // total ~30 MB

  feat_kernel<<<dim3((BATCH*(NS+NT))/8), 256, 0, stream>>>(
      sp,tp,Wss1,Wss2,Wqst,bqst,Wkst,bkst,Wqts,bqts,Wkts,bkts,
      FShi,FSlo,FThi,FTlo);

  // ---- phase 1: relu-max per region (no stores) ----
  adj_mfma<3,0><<<dim3(16,32,BATCH), 256, 0, stream>>>(   // ss K=96
      FShi,FSlo,FS_STRIDE,NS, 0,32,64,
      FShi,FSlo,FS_STRIDE,NS, 0,96,128,
      out, 0,0, maxs+0, 0);
  adj_mfma<2,0><<<dim3(1,32,BATCH), 256, 0, stream>>>(    // st K=64
      FShi,FSlo,FS_STRIDE,NS, 0,160,0,
      FThi,FTlo,FT_STRIDE,NT, 0,64,0,
      out, 0,NS, maxs+1, 0);
  adj_mfma<2,0><<<dim3(16,2,BATCH), 256, 0, stream>>>(    // ts K=64
      FThi,FTlo,FT_STRIDE,NT, 0,32,0,
      FShi,FSlo,FS_STRIDE,NS, 0,192,0,
      out, NS,0, maxs+2, 0);
  adj_mfma<1,0><<<dim3(1,2,BATCH), 256, 0, stream>>>(     // tt K=32
      FThi,FTlo,FT_STRIDE,NT, 0,0,0,
      FThi,FTlo,FT_STRIDE,NT, 0,0,0,
      out, NS,NS, maxs+3, 0);

  // ---- phase 2: recompute + normalize + store ----
  adj_mfma<3,1><<<dim3(16,32,BATCH), 256, 0, stream>>>(   // ss
      FShi,FSlo,FS_STRIDE,NS, 0,32,64,
      FShi,FSlo,FS_STRIDE,NS, 0,96,128,
      out, 0,0, maxs+0, 0);
  adj_mfma<2,1><<<dim3(1,32,BATCH), 256, 0, stream>>>(    // st
      FShi,FSlo,FS_STRIDE,NS, 0,160,0,
      FThi,FTlo,FT_STRIDE,NT, 0,64,0,
      out, 0,NS, maxs+1, 0);
  adj_mfma<2,1><<<dim3(16,2,BATCH), 256, 0, stream>>>(    // ts
      FThi,FTlo,FT_STRIDE,NT, 0,32,0,
      FShi,FSlo,FS_STRIDE,NS, 0,192,0,
      out, NS,0, maxs+2, 0);
  adj_mfma<1,1><<<dim3(1,2,BATCH), 256, 0, stream>>>(     // tt (+triu)
      FThi,FTlo,FT_STRIDE,NT, 0,0,0,
      FThi,FTlo,FT_STRIDE,NT, 0,0,0,
      out, NS,NS, maxs+3, 1);
}